// Round 13
// baseline (1566.972 us; speedup 1.0000x reference)
//
#include <hip/hip_runtime.h>

// LSTM char-RNN forward: batch=1024, T=512, UNITS=256, NUM_CHARS=128.
// R13 = R12 + dual-publish. R12 proved agent-scope stores write AROUND the
// local L2 (FETCH stayed 268MB; sc0 polls missed) -> the exchange pays the
// full L3 round trip. Fix on the STORE side: publish the tagged u64 twice:
// (1) workgroup-scope atomic store -> plain store that lands in the
// producer's XCD L2 (same-XCD sibling's sc0 poll hits it in ~250cyc);
// (2) agent-scope store -> L3 (cross-XCD correctness; consumer's every-8th
// escalation load sees it). Identical bits both stores; tag validation
// rejects stale reads; no path decision anywhere -> no split-brain, worst
// case degrades to R8-exact. Arithmetic unchanged -> absmax 6.1e-5.

#define TSTEPS 512
#define UNITS  256
#define NCHAR  128
#define G4     1024
#define ZS     516   // zbuf row stride

typedef float    f32x4 __attribute__((ext_vector_type(4)));
typedef _Float16 f16x8 __attribute__((ext_vector_type(8)));

union FU { uint4 u4; f16x8 h8; _Float16 h[8]; };
union HP { unsigned int u; _Float16 f[2]; };

__device__ __forceinline__ float fast_rcp(float x) {
#if __has_builtin(__builtin_amdgcn_rcpf)
  return __builtin_amdgcn_rcpf(x);
#else
  return 1.0f / x;
#endif
}
__device__ __forceinline__ float sigm(float x)  { return fast_rcp(1.0f + __expf(-x)); }
__device__ __forceinline__ float tanhx(float x) { return 2.0f * fast_rcp(1.0f + __expf(-2.0f * x)) - 1.0f; }

// L1-bypassing 8B load served by the (shared, same-XCD) L2. Blocking.
// [R12-proven on this toolchain]
__device__ __forceinline__ unsigned long long load_l2_u64(
    const unsigned long long* p) {
  unsigned long long v;
  asm volatile("global_load_dwordx2 %0, %1, off sc0\n\t"
               "s_waitcnt vmcnt(0)"
               : "=v"(v) : "v"(p) : "memory");
  return v;
}

// Tag-validated poll: fast L2 loads, agent-scope escalation every 8th try.
__device__ __forceinline__ unsigned long long poll_tagged(
    const unsigned long long* src, unsigned want) {
  unsigned long long v;
  long tries = 0;
  do {
    if ((tries & 7) == 7)
      v = __hip_atomic_load(src, __ATOMIC_RELAXED, __HIP_MEMORY_SCOPE_AGENT);
    else
      v = load_l2_u64(src);
  } while ((unsigned)(v >> 32) != want && ++tries < (1L << 18));
  return v;
}

// Dual-publish: local-L2 store (fast same-XCD visibility) + L3 store
// (cross-XCD correctness). Same bits; consumer sees whichever first.
__device__ __forceinline__ void publish_tagged(unsigned long long* dst,
                                               unsigned long long val) {
  __hip_atomic_store(dst, val, __ATOMIC_RELAXED, __HIP_MEMORY_SCOPE_WORKGROUP);
  asm volatile("" ::: "memory");   // keep both stores
  __hip_atomic_store(dst, val, __ATOMIC_RELAXED, __HIP_MEMORY_SCOPE_AGENT);
}

// ---- Prep: WhB = Wh fp16 B-fragment stream (R8-proven, unchanged).
__global__ void prep_whB(const float* __restrict__ Wh, uint4* __restrict__ WhB) {
  int idx = blockIdx.x * blockDim.x + threadIdx.x;    // 0..32767
  int l    = idx & 63;
  int kk   = (idx >> 6) & 7;
  int tile = (idx >> 9) & 31;
  int cc   = idx >> 14;
  int n    = tile * 16 + (l & 15);
  int gate = n & 3;
  int col  = gate * 256 + cc * 128 + (n >> 2);
  int kb   = kk * 32 + (l >> 4) * 8;
  FU p;
#pragma unroll
  for (int j = 0; j < 8; ++j)
    p.h[j] = (_Float16)Wh[(kb + j) * G4 + col];
  WhB[idx] = p.u4;
}

// ---- Prep: Wxbg[ch][u] = float4(i,f,g,o) = Wx[ch][gate*256+u] + b
__global__ void prep_wx(const float* __restrict__ Wx, const float* __restrict__ bias,
                        float4* __restrict__ Wxbg) {
  int idx = blockIdx.x * blockDim.x + threadIdx.x;    // 0..32767
  int u  = idx & (UNITS - 1);
  int ch = idx >> 8;
  const float* r = Wx + ch * G4;
  float4 o;
  o.x = r[0 * UNITS + u] + bias[0 * UNITS + u];
  o.y = r[1 * UNITS + u] + bias[1 * UNITS + u];
  o.z = r[2 * UNITS + u] + bias[2 * UNITS + u];
  o.w = r[3 * UNITS + u] + bias[3 * UNITS + u];
  Wxbg[idx] = o;
}

// A-frag LDS byte address for h element (row m, k).
__device__ __forceinline__ int afrag_addr(int k, int m) {
  return ((k >> 5) << 10) + (((((k >> 3) & 3) << 4) + m) << 4) + ((k & 7) << 1);
}

// ---- Main: 128 blocks x 1024 threads. (g = bid&63, c = bid>>6).
__global__ __launch_bounds__(1024) void lstm_mfma(
    const int* __restrict__ inp, const uint4* __restrict__ WhB,
    const float4* __restrict__ Wxbg, const float* __restrict__ Wd,
    const float* __restrict__ bd, float* __restrict__ out,
    unsigned long long* __restrict__ hx2) {
  __shared__ __align__(16) uint4 hfrag[512];     // 8 KB: h_t A-frags (K=256)
  __shared__ float zbuf[16 * ZS];                // 33 KB
  __shared__ float lgts[16 * 132];               // 8.4 KB
  __shared__ float rmax[16], rsum[16];

  const int tid  = threadIdx.x;
  const int lane = tid & 63;
  const int wv   = tid >> 6;          // 0..15 == batch row within group
  const int bid  = blockIdx.x;
  const int g    = bid & 63;
  const int c    = bid >> 6;          // column half
  const int row0 = g * 16;

  // ---- Weight B-frags, own-half kk's in slots 0..3, sibling-half in 4..7.
  FU wf0[8], wf1[8];
#pragma unroll
  for (int kx = 0; kx < 8; ++kx) {
    int kk = (kx < 4) ? (c * 4 + kx) : ((1 - c) * 4 + (kx - 4));
    wf0[kx].u4 = WhB[((c * 32 + wv * 2)     * 8 + kk) * 64 + lane];
    wf1[kx].u4 = WhB[((c * 32 + wv * 2 + 1) * 8 + kk) * 64 + lane];
  }
#pragma unroll
  for (int kx = 0; kx < 8; ++kx) {
    asm volatile("" : "+v"(wf0[kx].u4.x), "+v"(wf0[kx].u4.y), "+v"(wf0[kx].u4.z), "+v"(wf0[kx].u4.w));
    asm volatile("" : "+v"(wf1[kx].u4.x), "+v"(wf1[kx].u4.y), "+v"(wf1[kx].u4.z), "+v"(wf1[kx].u4.w));
  }

  if (tid < 512) hfrag[tid] = uint4{0u, 0u, 0u, 0u};   // h_0 = 0
  float cst0 = 0.f, cst1 = 0.f;
  __syncthreads();
  const int kown = c * 4, ksib = (1 - c) * 4;
  const int cs   = 1 - c;

  for (int t = 0; t < TSTEPS; ++t) {
    int    ch  = inp[(row0 + wv) * TSTEPS + t];
    float4 xb0 = Wxbg[ch * 256 + c * 128 + lane];
    float4 xb1 = Wxbg[ch * 256 + c * 128 + 64 + lane];

    // ---- own-half K MFMA first (fills the publish->poll gap); t=0: h=0
    f32x4 acc0 = {0.f, 0.f, 0.f, 0.f}, acc1 = {0.f, 0.f, 0.f, 0.f};
#pragma unroll
    for (int kx = 0; kx < 4; ++kx) {
      FU a; a.u4 = hfrag[(kown + kx) * 64 + lane];
      acc0 = __builtin_amdgcn_mfma_f32_16x16x32_f16(a.h8, wf0[kx].h8, acc0, 0, 0, 0);
      acc1 = __builtin_amdgcn_mfma_f32_16x16x32_f16(a.h8, wf1[kx].h8, acc1, 0, 0, 0);
    }

    if (t > 0) {
      // ---- fused detect+gather: L2 poll with agent escalation
      const int par = t & 1;
      const unsigned long long* src =
          &hx2[((par * 64 + g) * 2 + cs) * 1024 + tid];
      unsigned long long v = poll_tagged(src, (unsigned)t);
      HP hv; hv.u = (unsigned)v;
      const int r = tid >> 6, up = tid & 63;
      const int ka = cs * 128 + up;
      *(_Float16*)((char*)hfrag + afrag_addr(ka,      r)) = hv.f[0];
      *(_Float16*)((char*)hfrag + afrag_addr(ka + 64, r)) = hv.f[1];
      __syncthreads();
    }

    // ---- sibling-half K MFMA
#pragma unroll
    for (int kx = 0; kx < 4; ++kx) {
      FU a; a.u4 = hfrag[(ksib + kx) * 64 + lane];
      acc0 = __builtin_amdgcn_mfma_f32_16x16x32_f16(a.h8, wf0[4 + kx].h8, acc0, 0, 0, 0);
      acc1 = __builtin_amdgcn_mfma_f32_16x16x32_f16(a.h8, wf1[4 + kx].h8, acc1, 0, 0, 0);
    }
    {
      const int cq = lane >> 4, cn = lane & 15;   // C: row=(lane>>4)*4+reg
#pragma unroll
      for (int reg = 0; reg < 4; ++reg) {
        zbuf[(cq * 4 + reg) * ZS + (wv * 2)     * 16 + cn] = acc0[reg];
        zbuf[(cq * 4 + reg) * ZS + (wv * 2 + 1) * 16 + cn] = acc1[reg];
      }
    }
    __syncthreads();   // zbuf ready

    // ---- gates: thread = (row wv, units u0 = c*128+lane, u1 = u0+64)
    {
      float4 z0 = *(const float4*)&zbuf[wv * ZS + lane * 4];
      float4 z1 = *(const float4*)&zbuf[wv * ZS + lane * 4 + 256];
      float i0 = sigm(z0.x + xb0.x), f0 = sigm(z0.y + xb0.y);
      float g0 = tanhx(z0.z + xb0.z), o0 = sigm(z0.w + xb0.w);
      cst0 = f0 * cst0 + i0 * g0;
      float h0 = o0 * tanhx(cst0);
      float i1 = sigm(z1.x + xb1.x), f1 = sigm(z1.y + xb1.y);
      float g1 = tanhx(z1.z + xb1.z), o1 = sigm(z1.w + xb1.w);
      cst1 = f1 * cst1 + i1 * g1;
      float h1 = o1 * tanhx(cst1);

      HP p; p.f[0] = (_Float16)h0; p.f[1] = (_Float16)h1;
      // publish FIRST (latency-critical), then own-half LDS writes
      const int par1 = (t + 1) & 1;
      unsigned long long val =
          ((unsigned long long)(unsigned)(t + 1) << 32) | (unsigned long long)p.u;
      publish_tagged(&hx2[((par1 * 64 + g) * 2 + c) * 1024 + tid], val);
      const int ka = c * 128 + lane;
      *(_Float16*)((char*)hfrag + afrag_addr(ka,      wv)) = p.f[0];
      *(_Float16*)((char*)hfrag + afrag_addr(ka + 64, wv)) = p.f[1];
    }
    __syncthreads();   // hfrag own-half + zbuf handoff for next iteration
  }

  if (c != 0) return;

  // ---- Epilogue (c==0): poll h_T (tag==TSTEPS, par=0) -> fp32, Wd, softmax
  {
    const int r = tid >> 6, up = tid & 63;
#pragma unroll
    for (int half = 0; half < 2; ++half) {
      const unsigned long long* src = &hx2[(g * 2 + half) * 1024 + tid];
      unsigned long long v = poll_tagged(src, (unsigned)TSTEPS);
      HP hv; hv.u = (unsigned)v;
      zbuf[r * ZS + half * 128 + up]      = (float)hv.f[0];
      zbuf[r * ZS + half * 128 + up + 64] = (float)hv.f[1];
    }
  }
  __syncthreads();
  {
    const int j  = tid & 127;
    const int rb = tid >> 7;            // 0..7 -> rows 2rb, 2rb+1
    const int r0 = rb * 2, r1 = r0 + 1;
    float l0 = bd[j], l1 = bd[j];
    for (int k = 0; k < 256; ++k) {
      float w = Wd[k * NCHAR + j];
      l0 += zbuf[r0 * ZS + k] * w;
      l1 += zbuf[r1 * ZS + k] * w;
    }
    lgts[r0 * 132 + j] = l0;
    lgts[r1 * 132 + j] = l1;
  }
  __syncthreads();
  if (tid < 16) {
    const int r = tid;
    float m = -1e30f;
    for (int j = 0; j < NCHAR; ++j) m = fmaxf(m, lgts[r * 132 + j]);
    float s = 0.f;
    for (int j = 0; j < NCHAR; ++j) s += __expf(lgts[r * 132 + j] - m);
    rmax[r] = m;
    rsum[r] = fast_rcp(s);
  }
  __syncthreads();
  {
    const int j  = tid & 127;
    const int rb = tid >> 7;
#pragma unroll
    for (int ii = 0; ii < 2; ++ii) {
      int r = rb * 2 + ii;
      out[(row0 + r) * NCHAR + j] = __expf(lgts[r * 132 + j] - rmax[r]) * rsum[r];
    }
  }
}

extern "C" void kernel_launch(void* const* d_in, const int* in_sizes, int n_in,
                              void* d_out, int out_size, void* d_ws, size_t ws_size,
                              hipStream_t stream) {
  const int*   inp = (const int*)d_in[0];
  const float* Wx  = (const float*)d_in[1];
  const float* Wh  = (const float*)d_in[2];
  const float* bia = (const float*)d_in[3];
  const float* Wd  = (const float*)d_in[4];
  const float* bd  = (const float*)d_in[5];

  uint4*              WhB  = (uint4*)d_ws;                          // 512 KB
  float4*             Wxbg = (float4*)((char*)d_ws + (512 << 10));  // 512 KB
  unsigned long long* hx2  = (unsigned long long*)((char*)d_ws + (1 << 20)); // 2 MB

  prep_whB<<<128, 256, 0, stream>>>(Wh, WhB);
  prep_wx<<<128, 256, 0, stream>>>(Wx, bia, Wxbg);
  lstm_mfma<<<128, 1024, 0, stream>>>(inp, WhB, Wxbg, Wd, bd, (float*)d_out,
                                      hx2);
}